// Round 3
// baseline (206.639 us; speedup 1.0000x reference)
//
#include <hip/hip_runtime.h>

typedef unsigned short u16;
typedef unsigned char u8;
typedef unsigned int u32;
typedef float f32x4 __attribute__((ext_vector_type(4)));
typedef __bf16 bf16x8 __attribute__((ext_vector_type(8)));

#define ELEMS 25165824   // T*B*C*N bytes per spike branch = 4*16*384*1024
#define COLS_B 4096      // N*T per batch element
#define ONE_BF16 ((u16)0x3F80)

// ---- async global->LDS, 16B per lane, dest = wave-uniform base + lane*16 ----
__device__ __forceinline__ void gll16(const void* g, void* l) {
  __builtin_amdgcn_global_load_lds((const __attribute__((address_space(1))) void*)g,
                                   (__attribute__((address_space(3))) void*)l, 16, 0, 0);
}

// counted-vmcnt + raw barrier sync point (loads stay in flight across barriers)
#define SYNCP(n) do { \
    asm volatile("s_waitcnt vmcnt(" #n ")" ::: "memory"); \
    __builtin_amdgcn_s_barrier(); \
    asm volatile("" ::: "memory"); \
  } while (0)

// ---------------- K0: weights -> bf16 (stacked q,k,v), BN params fused ----------------
__global__ __launch_bounds__(256) void k_convert(
    const float* __restrict__ qw, const float* __restrict__ kw,
    const float* __restrict__ vw, const float* __restrict__ pw,
    const float* __restrict__ qg, const float* __restrict__ qbt,
    const float* __restrict__ qm, const float* __restrict__ qv,
    const float* __restrict__ kg, const float* __restrict__ kbt,
    const float* __restrict__ km, const float* __restrict__ kv,
    const float* __restrict__ vg, const float* __restrict__ vbt,
    const float* __restrict__ vm, const float* __restrict__ vv,
    const float* __restrict__ pg, const float* __restrict__ pbt,
    const float* __restrict__ pm, const float* __restrict__ pv,
    const float* __restrict__ pbias,
    u16* __restrict__ Wstk, u16* __restrict__ Pw,
    float4* __restrict__ BNP, float4* __restrict__ PP) {
  int tid = blockIdx.x * 256 + threadIdx.x;
  if (tid < 442368) {               // Wstk[1152][384]
    int r = tid / 384, c = tid - r * 384;
    const float* src = (r < 384) ? qw : (r < 768) ? kw : vw;
    int rr = (r >= 768) ? r - 768 : (r >= 384) ? r - 384 : r;
    unsigned int u = __float_as_uint(src[rr * 384 + c]);
    u = (u + 0x7FFFu + ((u >> 16) & 1u)) >> 16;   // RNE to bf16
    Wstk[tid] = (u16)u;
  } else if (tid < 589824) {        // Pw[384][384]
    int i = tid - 442368;
    unsigned int u = __float_as_uint(pw[i]);
    u = (u + 0x7FFFu + ((u >> 16) & 1u)) >> 16;
    Pw[i] = (u16)u;
  } else if (tid < 590976) {        // BNP[1152] = {inv, mean, beta, -}
    int r = tid - 589824;
    int br = r / 384, ch = r - br * 384;
    const float* g  = (br == 0) ? qg  : (br == 1) ? kg  : vg;
    const float* bt = (br == 0) ? qbt : (br == 1) ? kbt : vbt;
    const float* m  = (br == 0) ? qm  : (br == 1) ? km  : vm;
    const float* va = (br == 0) ? qv  : (br == 1) ? kv  : vv;
    float inv = g[ch] / sqrtf(va[ch] + 1e-5f);
    BNP[r] = make_float4(inv, m[ch], bt[ch], 0.f);
  } else if (tid < 591360) {        // PP[384] = {inv, mean, beta, bias}
    int ch = tid - 590976;
    float inv = pg[ch] / sqrtf(pv[ch] + 1e-5f);
    PP[ch] = make_float4(inv, pm[ch], pbt[ch], pbias[ch]);
  }
}

// ---------------- K1: input LIF + transpose (T,B,C,N)->(B,N,T,C) bf16 spikes ----------
__global__ __launch_bounds__(256) void k_lif_in(const float* __restrict__ x, u16* __restrict__ xs) {
  const int nt = blockIdx.x, ct = blockIdx.y, b = blockIdx.z;
  const int tid = threadIdx.x;
  const int nj = tid & 63, cr = tid >> 6;
  const int c0 = ct * 64, n0 = nt * 64;
  __shared__ u16 spl[16384];        // [nj][t][ci], ci XOR-swizzled by nj (quad-preserving)
  float v[16];
  #pragma unroll
  for (int i = 0; i < 16; ++i) v[i] = 0.f;
  for (int t = 0; t < 4; ++t) {
    const float* xr = x + (((t * 16 + b) * 384 + c0 + cr) * 1024) + n0 + nj;
    #pragma unroll
    for (int it = 0; it < 16; ++it) {
      float xv = xr[it * 4096];
      float vv = v[it];
      float h = __fadd_rn(vv, __fmul_rn(__fsub_rn(xv, vv), 0.5f));  // v + (x-v)/2, exact order
      bool s = h >= 1.f;
      v[it] = s ? 0.f : h;
      int ci = cr + it * 4;
      spl[((nj * 4 + t) << 6) | (ci ^ ((nj & 15) << 2))] = s ? ONE_BF16 : (u16)0;
    }
  }
  __syncthreads();
  #pragma unroll
  for (int kk = 0; kk < 16; ++kk) {
    int f = tid + kk * 256;
    int ci4 = f & 15, tt = (f >> 4) & 3, njj = f >> 6;
    ushort4 d = *(const ushort4*)&spl[((njj * 4 + tt) << 6) + ((ci4 * 4) ^ ((njj & 15) << 2))];
    *(ushort4*)&xs[((b * 1024 + n0 + njj) * 4 + tt) * 384 + c0 + ci4 * 4] = d;
  }
}

// ======================================================================================
// Pipelined GEMM core: BM=128 (c rows of weight), BN=256 (j cols = 64 n x 4 t), BK=64.
// 512 threads = 8 waves (4 j-groups x 2 c-groups), per-wave 64j x 64c = 4x4 MFMA tiles.
// LDS buffer (48KB): [Wk0 8K][Wk1 8K][Xk0 16K][Xk1 16K], 64B k-plane rows (no conflicts).
// 3 buffers, 2 K-tiles in flight, vmcnt(6) per iter (6 gll16 per tile per thread).
// ======================================================================================
#define STAGE(lds_, bufi, kt, Wp, Xp) do { \
    const u16* ws_ = (Wp) + (kt) * 64; \
    const u16* xs_ = (Xp) + (kt) * 64; \
    u16* lb_ = &lds_[(bufi) * 24576 + wbase]; \
    gll16(ws_,                  lb_ + 0 * 4096); \
    gll16(ws_ + 32,             lb_ + 1 * 4096); \
    gll16(xs_,                  lb_ + 2 * 4096); \
    gll16(xs_ + 128 * 384,      lb_ + 3 * 4096); \
    gll16(xs_ + 32,             lb_ + 4 * 4096); \
    gll16(xs_ + 128 * 384 + 32, lb_ + 5 * 4096); \
  } while (0)

#define COMPUTE(lds_, bufi) do { \
    const u16* lb_ = &lds_[(bufi) * 24576]; \
    _Pragma("unroll") \
    for (int ks = 0; ks < 2; ++ks) { \
      bf16x8 ax[4], bw[4]; \
      _Pragma("unroll") \
      for (int ji = 0; ji < 4; ++ji) \
        ax[ji] = *(const bf16x8*)&lb_[8192 + ks * 8192 + (wjg * 64 + ji * 16 + l15) * 32 + g * 8]; \
      _Pragma("unroll") \
      for (int ci = 0; ci < 4; ++ci) \
        bw[ci] = *(const bf16x8*)&lb_[ks * 4096 + (wcg * 64 + ci * 16 + l15) * 32 + g * 8]; \
      _Pragma("unroll") \
      for (int ji = 0; ji < 4; ++ji) \
        _Pragma("unroll") \
        for (int ci = 0; ci < 4; ++ci) \
          acc[ji][ci] = __builtin_amdgcn_mfma_f32_16x16x32_bf16(ax[ji], bw[ci], acc[ji][ci], 0, 0, 0); \
    } \
  } while (0)

#define GEMM_PIPELINE(lds_, Wp, Xp) do { \
    STAGE(lds_, 0, 0, Wp, Xp); STAGE(lds_, 1, 1, Wp, Xp); \
    SYNCP(6); STAGE(lds_, 2, 2, Wp, Xp); COMPUTE(lds_, 0); \
    SYNCP(6); STAGE(lds_, 0, 3, Wp, Xp); COMPUTE(lds_, 1); \
    SYNCP(6); STAGE(lds_, 1, 4, Wp, Xp); COMPUTE(lds_, 2); \
    SYNCP(6); STAGE(lds_, 2, 5, Wp, Xp); COMPUTE(lds_, 0); \
    SYNCP(6); COMPUTE(lds_, 1); \
    SYNCP(0); COMPUTE(lds_, 2); \
  } while (0)

// ---------------- K2: stacked qkv GEMM + BN + LIF -> sp u32 (4 t-bytes per (n,c)) -----
__global__ __launch_bounds__(512, 2) void k_qkv(
    const u16* __restrict__ Wstk, const u16* __restrict__ xs,
    const float4* __restrict__ BNP, u8* __restrict__ sp) {
  const int jt = blockIdx.x, mt = blockIdx.y;
  const int tid = threadIdx.x;
  const int w = tid >> 6;
  const int wjg = w >> 1, wcg = w & 1;
  const int l15 = tid & 15, g = (tid & 63) >> 4;
  const int m0 = mt * 128, j0 = jt * 256;
  const int wbase = w * 512;                      // u16: wave's 1KB slice within a plane

  __shared__ u16 lds[73728];                      // 3 x 48KB buffers
  __shared__ float4 PRM[128];

  if (tid < 128) PRM[tid] = BNP[m0 + tid];
  __syncthreads();                                // also drains PRM loads (vmcnt clean)

  const u16* Wp = Wstk + (m0 + (tid >> 2)) * 384 + (tid & 3) * 8;
  const u16* Xp = xs + (j0 + (tid >> 2)) * 384 + (tid & 3) * 8;

  f32x4 acc[4][4];
  const f32x4 zero = {0.f, 0.f, 0.f, 0.f};
  #pragma unroll
  for (int ji = 0; ji < 4; ++ji)
    #pragma unroll
    for (int ci = 0; ci < 4; ++ci) acc[ji][ci] = zero;

  GEMM_PIPELINE(lds, Wp, Xp);

  // epilogue: BN + 4-step LIF per lane (regs r = t), pack 4 spike bytes -> one u32
  const int br = mt / 3;
  const int cb = (mt - br * 3) * 128;
  u32* spW = (u32*)(sp + (size_t)br * ELEMS);
  #pragma unroll
  for (int ci = 0; ci < 4; ++ci) {
    const int c_loc = wcg * 64 + ci * 16 + l15;
    float4 pr = PRM[c_loc];
    #pragma unroll
    for (int ji = 0; ji < 4; ++ji) {
      f32x4 a = acc[ji][ci];
      u32 bytes = 0;
      float v = 0.f;
      #pragma unroll
      for (int t = 0; t < 4; ++t) {
        float z = __fadd_rn(__fmul_rn(__fsub_rn(a[t], pr.y), pr.x), pr.z);  // BN, ref order
        float h = __fadd_rn(v, __fmul_rn(__fsub_rn(z, v), 0.5f));            // LIF step
        bool s = h >= 1.f;
        v = s ? 0.f : h;
        bytes |= (s ? 1u : 0u) << (8 * t);
      }
      const int n_comb = jt * 64 + wjg * 16 + ji * 4 + g;
      spW[n_comb * 384 + cb + c_loc] = bytes;
    }
  }
}

// ---------------- K3: attn = sum_ch(k&v) per head (4 t in u32 bytes), LIF(0.5), xp ----
__global__ __launch_bounds__(256) void k_attn(const u8* __restrict__ sp, u16* __restrict__ xp) {
  const int gw = blockIdx.x * 4 + (threadIdx.x >> 6);
  const int l = threadIdx.x & 63;
  const int b = gw >> 10, n = gw & 1023;
  const u32* qB = (const u32*)sp;
  const u32* kB = (const u32*)(sp + ELEMS);
  const u32* vB = (const u32*)(sp + 2 * ELEMS);
  const int base = (b * 1024 + n) * 384 + l * 6;   // u32 index; lane covers 6 channels
  u32 qu[6], ku[6], vu[6];
  #pragma unroll
  for (int i = 0; i < 3; ++i) {
    *(uint2*)&qu[i * 2] = *(const uint2*)&qB[base + i * 2];
    *(uint2*)&ku[i * 2] = *(const uint2*)&kB[base + i * 2];
    *(uint2*)&vu[i * 2] = *(const uint2*)&vB[base + i * 2];
  }
  u32 s = 0;
  #pragma unroll
  for (int i = 0; i < 6; ++i) s += ku[i] & vu[i];   // 4 per-t byte sums in parallel
  s += __shfl_xor(s, 1);
  s += __shfl_xor(s, 2);
  s += __shfl_xor(s, 4);          // 8 lanes == one 48-channel head; bytes <= 48
  float v = 0.f;
  const int ob = ((b * 1024 + n) * 4) * 384 + l * 6;  // u16 index into xp
  #pragma unroll
  for (int t = 0; t < 4; ++t) {
    float attn = (float)((s >> (8 * t)) & 0xFFu);
    float h = __fadd_rn(v, __fmul_rn(__fsub_rn(attn, v), 0.5f));
    bool sk = h >= 0.5f;
    v = sk ? 0.f : h;
    u32 m = sk ? 0x3F80u : 0u;
    u32* dst = (u32*)(xp + ob + t * 384);
    #pragma unroll
    for (int i = 0; i < 3; ++i) {
      u32 lo = ((qu[2 * i]     >> (8 * t)) & 1u) ? m : 0u;
      u32 hi = ((qu[2 * i + 1] >> (8 * t)) & 1u) ? m : 0u;
      dst[i] = lo | (hi << 16);
    }
  }
}

// ---------------- K4: P GEMM + bias + BN -> out fp32 (LDS-transposed coalesced store) -
__global__ __launch_bounds__(512, 2) void k_proj(
    const u16* __restrict__ Pw, const u16* __restrict__ xp,
    const float4* __restrict__ PP, float* __restrict__ out) {
  const int jt = blockIdx.x, mt = blockIdx.y;
  const int tid = threadIdx.x;
  const int w = tid >> 6;
  const int wjg = w >> 1, wcg = w & 1;
  const int l15 = tid & 15, g = (tid & 63) >> 4;
  const int m0 = mt * 128, j0 = jt * 256;
  const int wbase = w * 512;

  __shared__ u16 lds[73728];
  __shared__ float4 PRM[128];

  if (tid < 128) PRM[tid] = PP[m0 + tid];
  __syncthreads();

  const u16* Wp = Pw + (m0 + (tid >> 2)) * 384 + (tid & 3) * 8;
  const u16* Xp = xp + (j0 + (tid >> 2)) * 384 + (tid & 3) * 8;

  f32x4 acc[4][4];
  const f32x4 zero = {0.f, 0.f, 0.f, 0.f};
  #pragma unroll
  for (int ji = 0; ji < 4; ++ji)
    #pragma unroll
    for (int ci = 0; ci < 4; ++ci) acc[ji][ci] = zero;

  GEMM_PIPELINE(lds, Wp, Xp);

  __syncthreads();                                 // full drain; loop done, LDS reusable
  float* scr = (float*)lds;                        // 128 x 68-padded f32 tile (34.8KB)
  const int b = jt >> 4;
  const int n0im = (jt & 15) * 64;

  #pragma unroll
  for (int t = 0; t < 4; ++t) {
    #pragma unroll
    for (int ci = 0; ci < 4; ++ci) {
      const int c_loc = wcg * 64 + ci * 16 + l15;
      float4 pr = PRM[c_loc];
      #pragma unroll
      for (int ji = 0; ji < 4; ++ji) {
        const int n_loc = wjg * 16 + ji * 4 + g;
        float zz = __fadd_rn(acc[ji][ci][t], pr.w);                        // + bias
        zz = __fadd_rn(__fmul_rn(__fsub_rn(zz, pr.y), pr.x), pr.z);        // BN, ref order
        scr[c_loc * 68 + n_loc] = zz;
      }
    }
    __syncthreads();
    #pragma unroll
    for (int it = 0; it < 4; ++it) {
      int slot = tid + it * 512;                   // 2048 slots = 128 rows x 16 float4
      int c = slot >> 4, li = slot & 15;
      float4 val = *(const float4*)&scr[c * 68 + li * 4];
      *(float4*)&out[(((size_t)(t * 16 + b) * 384) + m0 + c) * 1024 + n0im + li * 4] = val;
    }
    __syncthreads();
  }
}

extern "C" void kernel_launch(void* const* d_in, const int* in_sizes, int n_in,
                              void* d_out, int out_size, void* d_ws, size_t ws_size,
                              hipStream_t stream) {
  (void)in_sizes; (void)n_in; (void)out_size; (void)ws_size;
  const float* x   = (const float*)d_in[0];
  const float* qw  = (const float*)d_in[1];
  const float* qg  = (const float*)d_in[2];
  const float* qbt = (const float*)d_in[3];
  const float* qm  = (const float*)d_in[4];
  const float* qv  = (const float*)d_in[5];
  const float* kw  = (const float*)d_in[6];
  const float* kg  = (const float*)d_in[7];
  const float* kbt = (const float*)d_in[8];
  const float* km  = (const float*)d_in[9];
  const float* kv  = (const float*)d_in[10];
  const float* vw  = (const float*)d_in[11];
  const float* vg  = (const float*)d_in[12];
  const float* vbt = (const float*)d_in[13];
  const float* vm  = (const float*)d_in[14];
  const float* vv  = (const float*)d_in[15];
  const float* pw  = (const float*)d_in[16];
  const float* pg  = (const float*)d_in[17];
  const float* pbt = (const float*)d_in[18];
  const float* pm  = (const float*)d_in[19];
  const float* pv  = (const float*)d_in[20];
  const float* pbias = (const float*)d_in[21];

  char* ws = (char*)d_ws;
  u16* xs    = (u16*)ws;                    // (B,N,T,C) bf16 spikes; later reused as xp
  u8*  sp    = (u8*)(ws + 50331648);        // q,k,v spikes, u32 per (n,c): [b][n][c][t]
  u16* Wstk  = (u16*)(ws + 125829120);      // [1152][384] bf16
  u16* Pw    = (u16*)(ws + 126713856);      // [384][384] bf16
  float4* BNP = (float4*)(ws + 127008768);  // [1152]
  float4* PP  = (float4*)(ws + 127027200);  // [384]

  k_convert<<<2310, 256, 0, stream>>>(qw, kw, vw, pw, qg, qbt, qm, qv, kg, kbt, km, kv,
                                      vg, vbt, vm, vv, pg, pbt, pm, pv, pbias,
                                      Wstk, Pw, BNP, PP);
  k_lif_in<<<dim3(16, 6, 16), 256, 0, stream>>>(x, xs);
  k_qkv<<<dim3(256, 9), 512, 0, stream>>>(Wstk, xs, BNP, sp);
  k_attn<<<4096, 256, 0, stream>>>(sp, xs);          // xp aliases xs (xs dead after k_qkv)
  k_proj<<<dim3(256, 3), 512, 0, stream>>>(Pw, xs, PP, (float*)d_out);
}

// Round 4
// 149.791 us; speedup vs baseline: 1.3795x; 1.3795x over previous
//
#include <hip/hip_runtime.h>

typedef unsigned short u16;
typedef unsigned char u8;
typedef unsigned int u32;
typedef float f32x4 __attribute__((ext_vector_type(4)));
typedef __bf16 bf16x8 __attribute__((ext_vector_type(8)));

#define SPB 6291456      // bytes per spike branch: B*N*C = 16*1024*384 (u8, 4 t-bits)
#define ONE_BF16 ((u16)0x3F80)

// ---- async global->LDS, 16B per lane, dest = wave-uniform base + lane*16 ----
__device__ __forceinline__ void gll16(const void* g, void* l) {
  __builtin_amdgcn_global_load_lds((const __attribute__((address_space(1))) void*)g,
                                   (__attribute__((address_space(3))) void*)l, 16, 0, 0);
}

// counted-vmcnt + raw barrier sync point (loads stay in flight across barriers)
#define SYNCP(n) do { \
    asm volatile("s_waitcnt vmcnt(" #n ")" ::: "memory"); \
    __builtin_amdgcn_s_barrier(); \
    asm volatile("" ::: "memory"); \
  } while (0)

// ---------------- K0: weights -> bf16 (stacked q,k,v), BN params fused ----------------
__global__ __launch_bounds__(256) void k_convert(
    const float* __restrict__ qw, const float* __restrict__ kw,
    const float* __restrict__ vw, const float* __restrict__ pw,
    const float* __restrict__ qg, const float* __restrict__ qbt,
    const float* __restrict__ qm, const float* __restrict__ qv,
    const float* __restrict__ kg, const float* __restrict__ kbt,
    const float* __restrict__ km, const float* __restrict__ kv,
    const float* __restrict__ vg, const float* __restrict__ vbt,
    const float* __restrict__ vm, const float* __restrict__ vv,
    const float* __restrict__ pg, const float* __restrict__ pbt,
    const float* __restrict__ pm, const float* __restrict__ pv,
    const float* __restrict__ pbias,
    u16* __restrict__ Wstk, u16* __restrict__ Pw,
    float4* __restrict__ BNP, float4* __restrict__ PP) {
  int tid = blockIdx.x * 256 + threadIdx.x;
  if (tid < 442368) {               // Wstk[1152][384]
    int r = tid / 384, c = tid - r * 384;
    const float* src = (r < 384) ? qw : (r < 768) ? kw : vw;
    int rr = (r >= 768) ? r - 768 : (r >= 384) ? r - 384 : r;
    unsigned int u = __float_as_uint(src[rr * 384 + c]);
    u = (u + 0x7FFFu + ((u >> 16) & 1u)) >> 16;   // RNE to bf16
    Wstk[tid] = (u16)u;
  } else if (tid < 589824) {        // Pw[384][384]
    int i = tid - 442368;
    unsigned int u = __float_as_uint(pw[i]);
    u = (u + 0x7FFFu + ((u >> 16) & 1u)) >> 16;
    Pw[i] = (u16)u;
  } else if (tid < 590976) {        // BNP[1152] = {inv, mean, beta, -}
    int r = tid - 589824;
    int br = r / 384, ch = r - br * 384;
    const float* g  = (br == 0) ? qg  : (br == 1) ? kg  : vg;
    const float* bt = (br == 0) ? qbt : (br == 1) ? kbt : vbt;
    const float* m  = (br == 0) ? qm  : (br == 1) ? km  : vm;
    const float* va = (br == 0) ? qv  : (br == 1) ? kv  : vv;
    float inv = g[ch] / sqrtf(va[ch] + 1e-5f);
    BNP[r] = make_float4(inv, m[ch], bt[ch], 0.f);
  } else if (tid < 591360) {        // PP[384] = {inv, mean, beta, bias}
    int ch = tid - 590976;
    float inv = pg[ch] / sqrtf(pv[ch] + 1e-5f);
    PP[ch] = make_float4(inv, pm[ch], pbt[ch], pbias[ch]);
  }
}

// ---------------- K1: input LIF + transpose (T,B,C,N)->(B,N,T,C) bf16 spikes ----------
__global__ __launch_bounds__(256) void k_lif_in(const float* __restrict__ x, u16* __restrict__ xs) {
  const int nt = blockIdx.x, ct = blockIdx.y, b = blockIdx.z;
  const int tid = threadIdx.x;
  const int nj = tid & 63, cr = tid >> 6;
  const int c0 = ct * 64, n0 = nt * 64;
  __shared__ u16 spl[16384];        // [nj][t][ci], ci XOR-swizzled by nj (quad-preserving)
  float v[16];
  #pragma unroll
  for (int i = 0; i < 16; ++i) v[i] = 0.f;
  for (int t = 0; t < 4; ++t) {
    const float* xr = x + (((t * 16 + b) * 384 + c0 + cr) * 1024) + n0 + nj;
    #pragma unroll
    for (int it = 0; it < 16; ++it) {
      float xv = xr[it * 4096];
      float vv = v[it];
      float h = __fadd_rn(vv, __fmul_rn(__fsub_rn(xv, vv), 0.5f));  // v + (x-v)/2, exact order
      bool s = h >= 1.f;
      v[it] = s ? 0.f : h;
      int ci = cr + it * 4;
      spl[((nj * 4 + t) << 6) | (ci ^ ((nj & 15) << 2))] = s ? ONE_BF16 : (u16)0;
    }
  }
  __syncthreads();
  #pragma unroll
  for (int kk = 0; kk < 16; ++kk) {
    int f = tid + kk * 256;
    int ci4 = f & 15, tt = (f >> 4) & 3, njj = f >> 6;
    ushort4 d = *(const ushort4*)&spl[((njj * 4 + tt) << 6) + ((ci4 * 4) ^ ((njj & 15) << 2))];
    *(ushort4*)&xs[((b * 1024 + n0 + njj) * 4 + tt) * 384 + c0 + ci4 * 4] = d;
  }
}

// ======================================================================================
// Pipelined GEMM core: BM=128 (c rows), BN=256 (j cols = 64 n x 4 t), BK=64.
// 512 threads = 8 waves (4 j-groups x 2 c-groups), per-wave 64j x 64c = 4x4 MFMA tiles.
// LDS buffer (48KB): [Wk0 8K][Wk1 8K][Xk0 16K][Xk1 16K]; k-chunk XOR-swizzle (2-way max):
//   staging source chunk' = (tid&3) ^ ((tid>>3)&3)   (LDS dest linear, rule #21)
//   read slot            = g ^ ((l15>>1)&3)
// 3 buffers, 2 K-tiles in flight, vmcnt(6) per iter (6 gll16 per tile per thread).
// ======================================================================================
#define STAGE(lds_, bufi, kt, Wp, Xp) do { \
    const u16* ws_ = (Wp) + (kt) * 64; \
    const u16* xs_ = (Xp) + (kt) * 64; \
    u16* lb_ = &lds_[(bufi) * 24576 + wbase]; \
    gll16(ws_,                  lb_ + 0 * 4096); \
    gll16(ws_ + 32,             lb_ + 1 * 4096); \
    gll16(xs_,                  lb_ + 2 * 4096); \
    gll16(xs_ + 128 * 384,      lb_ + 3 * 4096); \
    gll16(xs_ + 32,             lb_ + 4 * 4096); \
    gll16(xs_ + 128 * 384 + 32, lb_ + 5 * 4096); \
  } while (0)

#define COMPUTE(lds_, bufi) do { \
    const u16* lb_ = &lds_[(bufi) * 24576]; \
    _Pragma("unroll") \
    for (int ks = 0; ks < 2; ++ks) { \
      bf16x8 ax[4], bw[4]; \
      _Pragma("unroll") \
      for (int ji = 0; ji < 4; ++ji) \
        ax[ji] = *(const bf16x8*)&lb_[8192 + ks * 8192 + (wjg * 64 + ji * 16 + l15) * 32 + swoff]; \
      _Pragma("unroll") \
      for (int ci = 0; ci < 4; ++ci) \
        bw[ci] = *(const bf16x8*)&lb_[ks * 4096 + (wcg * 64 + ci * 16 + l15) * 32 + swoff]; \
      _Pragma("unroll") \
      for (int ji = 0; ji < 4; ++ji) \
        _Pragma("unroll") \
        for (int ci = 0; ci < 4; ++ci) \
          acc[ji][ci] = __builtin_amdgcn_mfma_f32_16x16x32_bf16(ax[ji], bw[ci], acc[ji][ci], 0, 0, 0); \
    } \
  } while (0)

#define GEMM_PIPELINE(lds_, Wp, Xp) do { \
    STAGE(lds_, 0, 0, Wp, Xp); STAGE(lds_, 1, 1, Wp, Xp); \
    SYNCP(6); STAGE(lds_, 2, 2, Wp, Xp); COMPUTE(lds_, 0); \
    SYNCP(6); STAGE(lds_, 0, 3, Wp, Xp); COMPUTE(lds_, 1); \
    SYNCP(6); STAGE(lds_, 1, 4, Wp, Xp); COMPUTE(lds_, 2); \
    SYNCP(6); STAGE(lds_, 2, 5, Wp, Xp); COMPUTE(lds_, 0); \
    SYNCP(6); COMPUTE(lds_, 1); \
    SYNCP(0); COMPUTE(lds_, 2); \
  } while (0)

// ---------------- K2: stacked qkv GEMM + BN + LIF -> sp u8 (4 t-bits per (n,c)) -------
__global__ __launch_bounds__(512, 2) void k_qkv(
    const u16* __restrict__ Wstk, const u16* __restrict__ xs,
    const float4* __restrict__ BNP, u8* __restrict__ sp) {
  const int jt = blockIdx.x, mt = blockIdx.y, b = blockIdx.z;
  const int tid = threadIdx.x;
  const int w = tid >> 6;
  const int wjg = w >> 1, wcg = w & 1;
  const int l15 = tid & 15, g = (tid & 63) >> 4;
  const int swoff = (g ^ ((l15 >> 1) & 3)) * 8;   // swizzled read slot (u16 units)
  const int m0 = mt * 128, j0 = b * 4096 + jt * 256;
  const int wbase = w * 512;                      // u16: wave's 1KB slice within a plane

  __shared__ u16 lds[73728];                      // 3 x 48KB buffers
  __shared__ float4 PRM[128];

  if (tid < 128) PRM[tid] = BNP[m0 + tid];
  __syncthreads();                                // drains PRM loads (vmcnt clean)

  const int srow = tid >> 2;
  const int sch = (tid & 3) ^ ((tid >> 3) & 3);   // pre-swizzled global k-chunk
  const u16* Wp = Wstk + (m0 + srow) * 384 + sch * 8;
  const u16* Xp = xs + (j0 + srow) * 384 + sch * 8;

  f32x4 acc[4][4];
  const f32x4 zero = {0.f, 0.f, 0.f, 0.f};
  #pragma unroll
  for (int ji = 0; ji < 4; ++ji)
    #pragma unroll
    for (int ci = 0; ci < 4; ++ci) acc[ji][ci] = zero;

  GEMM_PIPELINE(lds, Wp, Xp);

  // epilogue: BN + 4-step LIF per lane (regs r = t), pack 4 spike bits -> one u8
  const int br = mt / 3;
  const int cb = (mt - br * 3) * 128;
  u8* spW = sp + (size_t)br * SPB;
  #pragma unroll
  for (int ci = 0; ci < 4; ++ci) {
    const int c_loc = wcg * 64 + ci * 16 + l15;
    float4 pr = PRM[c_loc];
    #pragma unroll
    for (int ji = 0; ji < 4; ++ji) {
      f32x4 a = acc[ji][ci];
      u32 bits = 0;
      float v = 0.f;
      #pragma unroll
      for (int t = 0; t < 4; ++t) {
        float z = __fadd_rn(__fmul_rn(__fsub_rn(a[t], pr.y), pr.x), pr.z);  // BN, ref order
        float h = __fadd_rn(v, __fmul_rn(__fsub_rn(z, v), 0.5f));            // LIF step
        bool s = h >= 1.f;
        v = s ? 0.f : h;
        bits |= (s ? 1u : 0u) << t;
      }
      const int n_comb = b * 1024 + jt * 64 + wjg * 16 + ji * 4 + g;
      spW[(size_t)n_comb * 384 + cb + c_loc] = (u8)bits;
    }
  }
}

// ---------------- K3: attn = sum_ch(k&v) per head (bit nibbles), LIF(0.5), xp bf16 ----
__global__ __launch_bounds__(256) void k_attn(const u8* __restrict__ sp, u16* __restrict__ xp) {
  const int gw = blockIdx.x * 4 + (threadIdx.x >> 6);
  const int l = threadIdx.x & 63;
  const int b = gw >> 10, n = gw & 1023;
  const u8* qB = sp;
  const u8* kB = sp + SPB;
  const u8* vB = sp + 2 * SPB;
  const int base = (b * 1024 + n) * 384 + l * 6;   // byte index; lane covers 6 channels
  u16 qu[3], ku[3], vu[3];
  #pragma unroll
  for (int i = 0; i < 3; ++i) {
    qu[i] = *(const u16*)(qB + base + 2 * i);
    ku[i] = *(const u16*)(kB + base + 2 * i);
    vu[i] = *(const u16*)(vB + base + 2 * i);
  }
  u32 s = 0;                        // 4 per-t byte sums packed in a u32
  #pragma unroll
  for (int i = 0; i < 3; ++i) {
    u32 a = (u32)(ku[i] & vu[i]);
    #pragma unroll
    for (int t = 0; t < 4; ++t) {
      u32 x = (a >> t) & 0x0101u;
      s += ((x + (x >> 8)) & 3u) << (8 * t);
    }
  }
  s += __shfl_xor(s, 1);
  s += __shfl_xor(s, 2);
  s += __shfl_xor(s, 4);            // 8 lanes == one 48-channel head; bytes <= 48
  float v = 0.f;
  const int ob = ((b * 1024 + n) * 4) * 384 + l * 6;  // u16 index into xp
  #pragma unroll
  for (int t = 0; t < 4; ++t) {
    float attn = (float)((s >> (8 * t)) & 0xFFu);
    float h = __fadd_rn(v, __fmul_rn(__fsub_rn(attn, v), 0.5f));
    bool sk = h >= 0.5f;
    v = sk ? 0.f : h;
    u32 m = sk ? 0x3F80u : 0u;
    u32* dst = (u32*)(xp + ob + t * 384);
    #pragma unroll
    for (int i = 0; i < 3; ++i) {
      u32 lo = ((qu[i] >> t) & 1u) ? m : 0u;
      u32 hi = ((qu[i] >> (8 + t)) & 1u) ? m : 0u;
      dst[i] = lo | (hi << 16);
    }
  }
}

// ---------------- K4: P GEMM + bias + BN -> out fp32 (LDS-transposed coalesced store) -
__global__ __launch_bounds__(512, 2) void k_proj(
    const u16* __restrict__ Pw, const u16* __restrict__ xp,
    const float4* __restrict__ PP, float* __restrict__ out) {
  const int jt = blockIdx.x, mt = blockIdx.y, b = blockIdx.z;
  const int tid = threadIdx.x;
  const int w = tid >> 6;
  const int wjg = w >> 1, wcg = w & 1;
  const int l15 = tid & 15, g = (tid & 63) >> 4;
  const int swoff = (g ^ ((l15 >> 1) & 3)) * 8;
  const int m0 = mt * 128, j0 = b * 4096 + jt * 256;
  const int wbase = w * 512;

  __shared__ u16 lds[73728];
  __shared__ float4 PRM[128];

  if (tid < 128) PRM[tid] = PP[m0 + tid];
  __syncthreads();

  const int srow = tid >> 2;
  const int sch = (tid & 3) ^ ((tid >> 3) & 3);
  const u16* Wp = Pw + (m0 + srow) * 384 + sch * 8;
  const u16* Xp = xp + (j0 + srow) * 384 + sch * 8;

  f32x4 acc[4][4];
  const f32x4 zero = {0.f, 0.f, 0.f, 0.f};
  #pragma unroll
  for (int ji = 0; ji < 4; ++ji)
    #pragma unroll
    for (int ci = 0; ci < 4; ++ci) acc[ji][ci] = zero;

  GEMM_PIPELINE(lds, Wp, Xp);

  __syncthreads();                                 // full drain; loop done, LDS reusable
  float* scr = (float*)lds;                        // 128 x 68-padded f32 tile (34.8KB)
  const int n0im = jt * 64;

  #pragma unroll
  for (int t = 0; t < 4; ++t) {
    #pragma unroll
    for (int ci = 0; ci < 4; ++ci) {
      const int c_loc = wcg * 64 + ci * 16 + l15;
      float4 pr = PRM[c_loc];
      #pragma unroll
      for (int ji = 0; ji < 4; ++ji) {
        const int n_loc = wjg * 16 + ji * 4 + g;
        float zz = __fadd_rn(acc[ji][ci][t], pr.w);                        // + bias
        zz = __fadd_rn(__fmul_rn(__fsub_rn(zz, pr.y), pr.x), pr.z);        // BN, ref order
        scr[c_loc * 68 + n_loc] = zz;
      }
    }
    __syncthreads();
    #pragma unroll
    for (int it = 0; it < 4; ++it) {
      int slot = tid + it * 512;                   // 2048 slots = 128 rows x 16 float4
      int c = slot >> 4, li = slot & 15;
      float4 val = *(const float4*)&scr[c * 68 + li * 4];
      *(float4*)&out[(((size_t)(t * 16 + b) * 384) + m0 + c) * 1024 + n0im + li * 4] = val;
    }
    __syncthreads();
  }
}

extern "C" void kernel_launch(void* const* d_in, const int* in_sizes, int n_in,
                              void* d_out, int out_size, void* d_ws, size_t ws_size,
                              hipStream_t stream) {
  (void)in_sizes; (void)n_in; (void)out_size; (void)ws_size;
  const float* x   = (const float*)d_in[0];
  const float* qw  = (const float*)d_in[1];
  const float* qg  = (const float*)d_in[2];
  const float* qbt = (const float*)d_in[3];
  const float* qm  = (const float*)d_in[4];
  const float* qv  = (const float*)d_in[5];
  const float* kw  = (const float*)d_in[6];
  const float* kg  = (const float*)d_in[7];
  const float* kbt = (const float*)d_in[8];
  const float* km  = (const float*)d_in[9];
  const float* kv  = (const float*)d_in[10];
  const float* vw  = (const float*)d_in[11];
  const float* vg  = (const float*)d_in[12];
  const float* vbt = (const float*)d_in[13];
  const float* vm  = (const float*)d_in[14];
  const float* vv  = (const float*)d_in[15];
  const float* pw  = (const float*)d_in[16];
  const float* pg  = (const float*)d_in[17];
  const float* pbt = (const float*)d_in[18];
  const float* pm  = (const float*)d_in[19];
  const float* pv  = (const float*)d_in[20];
  const float* pbias = (const float*)d_in[21];

  char* ws = (char*)d_ws;
  u16* xs    = (u16*)ws;                    // (B,N,T,C) bf16 spikes (50 MB); reused as xp
  u8*  sp    = (u8*)(ws + 50331648);        // q,k,v spike nibbles, u8 per (n,c): 3 x 6 MB
  u16* Wstk  = (u16*)(ws + 69206016);       // [1152][384] bf16
  u16* Pw    = (u16*)(ws + 70090752);       // [384][384] bf16
  float4* BNP = (float4*)(ws + 70385664);   // [1152]
  float4* PP  = (float4*)(ws + 70404096);   // [384]

  k_convert<<<2310, 256, 0, stream>>>(qw, kw, vw, pw, qg, qbt, qm, qv, kg, kbt, km, kv,
                                      vg, vbt, vm, vv, pg, pbt, pm, pv, pbias,
                                      Wstk, Pw, BNP, PP);
  k_lif_in<<<dim3(16, 6, 16), 256, 0, stream>>>(x, xs);
  k_qkv<<<dim3(16, 9, 16), 512, 0, stream>>>(Wstk, xs, BNP, sp);
  k_attn<<<4096, 256, 0, stream>>>(sp, xs);          // xp aliases xs (xs dead after k_qkv)
  k_proj<<<dim3(16, 3, 16), 512, 0, stream>>>(Pw, xs, PP, (float*)d_out);
}

// Round 5
// 142.366 us; speedup vs baseline: 1.4515x; 1.0522x over previous
//
#include <hip/hip_runtime.h>

typedef unsigned short u16;
typedef unsigned char u8;
typedef unsigned int u32;
typedef float f32x4 __attribute__((ext_vector_type(4)));
typedef __bf16 bf16x8 __attribute__((ext_vector_type(8)));

#define SPB 6291456      // bytes per spike branch: B*N*C = 16*1024*384 (u8, 4 t-bits)
#define ONE_BF16 ((u16)0x3F80)

// ---- async global->LDS, 16B per lane, dest = wave-uniform base + lane*16 ----
__device__ __forceinline__ void gll16(const void* g, void* l) {
  __builtin_amdgcn_global_load_lds((const __attribute__((address_space(1))) void*)g,
                                   (__attribute__((address_space(3))) void*)l, 16, 0, 0);
}

// counted-vmcnt + raw barrier sync point (loads stay in flight across barriers)
#define SYNCP(n) do { \
    asm volatile("s_waitcnt vmcnt(" #n ")" ::: "memory"); \
    __builtin_amdgcn_s_barrier(); \
    asm volatile("" ::: "memory"); \
  } while (0)

// ---------------- K0: weights -> bf16 (stacked q,k,v), BN params fused ----------------
__global__ __launch_bounds__(256) void k_convert(
    const float* __restrict__ qw, const float* __restrict__ kw,
    const float* __restrict__ vw, const float* __restrict__ pw,
    const float* __restrict__ qg, const float* __restrict__ qbt,
    const float* __restrict__ qm, const float* __restrict__ qv,
    const float* __restrict__ kg, const float* __restrict__ kbt,
    const float* __restrict__ km, const float* __restrict__ kv,
    const float* __restrict__ vg, const float* __restrict__ vbt,
    const float* __restrict__ vm, const float* __restrict__ vv,
    const float* __restrict__ pg, const float* __restrict__ pbt,
    const float* __restrict__ pm, const float* __restrict__ pv,
    const float* __restrict__ pbias,
    u16* __restrict__ Wstk, u16* __restrict__ Pw,
    float4* __restrict__ BNP, float4* __restrict__ PP) {
  int tid = blockIdx.x * 256 + threadIdx.x;
  if (tid < 442368) {               // Wstk[1152][384]
    int r = tid / 384, c = tid - r * 384;
    const float* src = (r < 384) ? qw : (r < 768) ? kw : vw;
    int rr = (r >= 768) ? r - 768 : (r >= 384) ? r - 384 : r;
    unsigned int u = __float_as_uint(src[rr * 384 + c]);
    u = (u + 0x7FFFu + ((u >> 16) & 1u)) >> 16;   // RNE to bf16
    Wstk[tid] = (u16)u;
  } else if (tid < 589824) {        // Pw[384][384]
    int i = tid - 442368;
    unsigned int u = __float_as_uint(pw[i]);
    u = (u + 0x7FFFu + ((u >> 16) & 1u)) >> 16;
    Pw[i] = (u16)u;
  } else if (tid < 590976) {        // BNP[1152] = {inv, mean, beta, -}
    int r = tid - 589824;
    int br = r / 384, ch = r - br * 384;
    const float* g  = (br == 0) ? qg  : (br == 1) ? kg  : vg;
    const float* bt = (br == 0) ? qbt : (br == 1) ? kbt : vbt;
    const float* m  = (br == 0) ? qm  : (br == 1) ? km  : vm;
    const float* va = (br == 0) ? qv  : (br == 1) ? kv  : vv;
    float inv = g[ch] / sqrtf(va[ch] + 1e-5f);
    BNP[r] = make_float4(inv, m[ch], bt[ch], 0.f);
  } else if (tid < 591360) {        // PP[384] = {inv, mean, beta, bias}
    int ch = tid - 590976;
    float inv = pg[ch] / sqrtf(pv[ch] + 1e-5f);
    PP[ch] = make_float4(inv, pm[ch], pbt[ch], pbias[ch]);
  }
}

// ---------------- K1: input LIF + transpose (T,B,C,N)->(B,N,T,C) bf16 spikes ----------
__global__ __launch_bounds__(256) void k_lif_in(const float* __restrict__ x, u16* __restrict__ xs) {
  const int nt = blockIdx.x, ct = blockIdx.y, b = blockIdx.z;
  const int tid = threadIdx.x;
  const int nj = tid & 63, cr = tid >> 6;
  const int c0 = ct * 64, n0 = nt * 64;
  __shared__ u16 spl[16384];        // [nj][t][ci], ci XOR-swizzled by nj (quad-preserving)
  float v[16];
  #pragma unroll
  for (int i = 0; i < 16; ++i) v[i] = 0.f;
  for (int t = 0; t < 4; ++t) {
    const float* xr = x + (((t * 16 + b) * 384 + c0 + cr) * 1024) + n0 + nj;
    #pragma unroll
    for (int it = 0; it < 16; ++it) {
      float xv = xr[it * 4096];
      float vv = v[it];
      float h = __fadd_rn(vv, __fmul_rn(__fsub_rn(xv, vv), 0.5f));  // v + (x-v)/2, exact order
      bool s = h >= 1.f;
      v[it] = s ? 0.f : h;
      int ci = cr + it * 4;
      spl[((nj * 4 + t) << 6) | (ci ^ ((nj & 15) << 2))] = s ? ONE_BF16 : (u16)0;
    }
  }
  __syncthreads();
  #pragma unroll
  for (int kk = 0; kk < 16; ++kk) {
    int f = tid + kk * 256;
    int ci4 = f & 15, tt = (f >> 4) & 3, njj = f >> 6;
    ushort4 d = *(const ushort4*)&spl[((njj * 4 + tt) << 6) + ((ci4 * 4) ^ ((njj & 15) << 2))];
    *(ushort4*)&xs[((b * 1024 + n0 + njj) * 4 + tt) * 384 + c0 + ci4 * 4] = d;
  }
}

// ======================================================================================
// Pipelined GEMM core v2: BM=128 (c rows), BN=256 (j cols = 64 n x 4 t), BK=32.
// 512 threads = 8 waves (4 j-groups x 2 c-groups), per-wave 64j x 64c = 4x4 MFMA tiles.
// Buffer (24KB = 12288 u16): [W 128x32 @0][X 256x32 @4096]; 3 buffers = 72KB ->
// 2 blocks/CU (16 waves). k-chunk XOR swizzle both-sides (2-way max conflicts).
// 12 K-tiles, 3 gll16/thread/stage, 2 stages in flight, SYNCP(3) per tile.
// ======================================================================================
#define STAGE(bufi, kt) do { \
    u16* lb_ = &lds[(bufi) * 12288 + wst]; \
    gll16(Wp  + (kt) * 32, lb_); \
    gll16(Xp0 + (kt) * 32, lb_ + 4096); \
    gll16(Xp1 + (kt) * 32, lb_ + 8192); \
  } while (0)

#define COMPUTE(bufi) do { \
    const u16* lb_ = &lds[(bufi) * 12288]; \
    bf16x8 ax[4], bw[4]; \
    _Pragma("unroll") \
    for (int ji = 0; ji < 4; ++ji) \
      ax[ji] = *(const bf16x8*)&lb_[4096 + (wjg * 64 + ji * 16 + l15) * 32 + swoff]; \
    _Pragma("unroll") \
    for (int ci = 0; ci < 4; ++ci) \
      bw[ci] = *(const bf16x8*)&lb_[(wcg * 64 + ci * 16 + l15) * 32 + swoff]; \
    __builtin_amdgcn_s_setprio(1); \
    _Pragma("unroll") \
    for (int ji = 0; ji < 4; ++ji) \
      _Pragma("unroll") \
      for (int ci = 0; ci < 4; ++ci) \
        acc[ji][ci] = __builtin_amdgcn_mfma_f32_16x16x32_bf16(ax[ji], bw[ci], acc[ji][ci], 0, 0, 0); \
    __builtin_amdgcn_s_setprio(0); \
  } while (0)

#define GEMM_PIPELINE() do { \
    STAGE(0, 0); STAGE(1, 1); \
    SYNCP(3); STAGE(2, 2);  COMPUTE(0); \
    SYNCP(3); STAGE(0, 3);  COMPUTE(1); \
    SYNCP(3); STAGE(1, 4);  COMPUTE(2); \
    SYNCP(3); STAGE(2, 5);  COMPUTE(0); \
    SYNCP(3); STAGE(0, 6);  COMPUTE(1); \
    SYNCP(3); STAGE(1, 7);  COMPUTE(2); \
    SYNCP(3); STAGE(2, 8);  COMPUTE(0); \
    SYNCP(3); STAGE(0, 9);  COMPUTE(1); \
    SYNCP(3); STAGE(1, 10); COMPUTE(2); \
    SYNCP(3); STAGE(2, 11); COMPUTE(0); \
    SYNCP(3); COMPUTE(1); \
    SYNCP(0); COMPUTE(2); \
  } while (0)

// per-thread staging geometry (both GEMMs):
//   lane row = l>>2, chunk pos = l&3, pre-swizzled source chunk = (l&3) ^ ((l>>3)&3)

// ---------------- K2: stacked qkv GEMM + BN + LIF -> sp u8 (4 t-bits per (n,c)) -------
__global__ __launch_bounds__(512, 4) void k_qkv(
    const u16* __restrict__ Wstk, const u16* __restrict__ xs,
    const float4* __restrict__ BNP, u8* __restrict__ sp) {
  const int jt = blockIdx.x, mt = blockIdx.y, b = blockIdx.z;
  const int tid = threadIdx.x;
  const int w = tid >> 6, l = tid & 63;
  const int wjg = w >> 1, wcg = w & 1;
  const int l15 = tid & 15, g = (tid & 63) >> 4;
  const int swoff = (g ^ ((l15 >> 1) & 3)) * 8;   // swizzled read slot (u16 units)
  const int m0 = mt * 128, j0 = b * 4096 + jt * 256;
  const int wst = w * 512;                        // wave's 1KB chunk slot

  __shared__ u16 lds[36864];                      // 3 x 24KB buffers
  __shared__ float4 PRM[128];

  if (tid < 128) PRM[tid] = BNP[m0 + tid];
  __syncthreads();                                // drains PRM loads (vmcnt clean)

  const int srow = l >> 2;
  const int sch = (l & 3) ^ ((l >> 3) & 3);       // pre-swizzled global k-chunk
  const u16* Wp  = Wstk + (m0 + w * 16 + srow) * 384 + sch * 8;
  const u16* Xp0 = xs + (j0 + w * 16 + srow) * 384 + sch * 8;
  const u16* Xp1 = Xp0 + 128 * 384;

  f32x4 acc[4][4];
  const f32x4 zero = {0.f, 0.f, 0.f, 0.f};
  #pragma unroll
  for (int ji = 0; ji < 4; ++ji)
    #pragma unroll
    for (int ci = 0; ci < 4; ++ci) acc[ji][ci] = zero;

  GEMM_PIPELINE();

  // epilogue: BN + 4-step LIF per lane (regs r = t), pack 4 spike bits -> one u8
  const int br = mt / 3;
  const int cb = (mt - br * 3) * 128;
  u8* spW = sp + (size_t)br * SPB;
  #pragma unroll
  for (int ci = 0; ci < 4; ++ci) {
    const int c_loc = wcg * 64 + ci * 16 + l15;
    float4 pr = PRM[c_loc];
    #pragma unroll
    for (int ji = 0; ji < 4; ++ji) {
      f32x4 a = acc[ji][ci];
      u32 bits = 0;
      float v = 0.f;
      #pragma unroll
      for (int t = 0; t < 4; ++t) {
        float z = __fadd_rn(__fmul_rn(__fsub_rn(a[t], pr.y), pr.x), pr.z);  // BN, ref order
        float h = __fadd_rn(v, __fmul_rn(__fsub_rn(z, v), 0.5f));            // LIF step
        bool s = h >= 1.f;
        v = s ? 0.f : h;
        bits |= (s ? 1u : 0u) << t;
      }
      const int n_comb = b * 1024 + jt * 64 + wjg * 16 + ji * 4 + g;
      spW[(size_t)n_comb * 384 + cb + c_loc] = (u8)bits;
    }
  }
}

// ---------------- K3: attn = sum_ch(k&v) per head (bit nibbles), LIF(0.5), xp bf16 ----
__global__ __launch_bounds__(256) void k_attn(const u8* __restrict__ sp, u16* __restrict__ xp) {
  const int gw = blockIdx.x * 4 + (threadIdx.x >> 6);
  const int l = threadIdx.x & 63;
  const int b = gw >> 10, n = gw & 1023;
  const u8* qB = sp;
  const u8* kB = sp + SPB;
  const u8* vB = sp + 2 * SPB;
  const int base = (b * 1024 + n) * 384 + l * 6;   // byte index; lane covers 6 channels
  u16 qu[3], ku[3], vu[3];
  #pragma unroll
  for (int i = 0; i < 3; ++i) {
    qu[i] = *(const u16*)(qB + base + 2 * i);
    ku[i] = *(const u16*)(kB + base + 2 * i);
    vu[i] = *(const u16*)(vB + base + 2 * i);
  }
  u32 s = 0;                        // 4 per-t byte sums packed in a u32
  #pragma unroll
  for (int i = 0; i < 3; ++i) {
    u32 a = (u32)(ku[i] & vu[i]);
    #pragma unroll
    for (int t = 0; t < 4; ++t) {
      u32 x = (a >> t) & 0x0101u;
      s += ((x + (x >> 8)) & 3u) << (8 * t);
    }
  }
  s += __shfl_xor(s, 1);
  s += __shfl_xor(s, 2);
  s += __shfl_xor(s, 4);            // 8 lanes == one 48-channel head; bytes <= 48
  float v = 0.f;
  const int ob = ((b * 1024 + n) * 4) * 384 + l * 6;  // u16 index into xp
  #pragma unroll
  for (int t = 0; t < 4; ++t) {
    float attn = (float)((s >> (8 * t)) & 0xFFu);
    float h = __fadd_rn(v, __fmul_rn(__fsub_rn(attn, v), 0.5f));
    bool sk = h >= 0.5f;
    v = sk ? 0.f : h;
    u32 m = sk ? 0x3F80u : 0u;
    u32* dst = (u32*)(xp + ob + t * 384);
    #pragma unroll
    for (int i = 0; i < 3; ++i) {
      u32 lo = ((qu[i] >> t) & 1u) ? m : 0u;
      u32 hi = ((qu[i] >> (8 + t)) & 1u) ? m : 0u;
      dst[i] = lo | (hi << 16);
    }
  }
}

// ---------------- K4: P GEMM + bias + BN -> out fp32 (LDS-transposed coalesced store) -
__global__ __launch_bounds__(512, 4) void k_proj(
    const u16* __restrict__ Pw, const u16* __restrict__ xp,
    const float4* __restrict__ PP, float* __restrict__ out) {
  const int jt = blockIdx.x, mt = blockIdx.y, b = blockIdx.z;
  const int tid = threadIdx.x;
  const int w = tid >> 6, l = tid & 63;
  const int wjg = w >> 1, wcg = w & 1;
  const int l15 = tid & 15, g = (tid & 63) >> 4;
  const int swoff = (g ^ ((l15 >> 1) & 3)) * 8;
  const int m0 = mt * 128, j0 = b * 4096 + jt * 256;
  const int wst = w * 512;

  __shared__ u16 lds[36864];
  __shared__ float4 PRM[128];

  if (tid < 128) PRM[tid] = PP[m0 + tid];
  __syncthreads();

  const int srow = l >> 2;
  const int sch = (l & 3) ^ ((l >> 3) & 3);
  const u16* Wp  = Pw + (m0 + w * 16 + srow) * 384 + sch * 8;
  const u16* Xp0 = xp + (j0 + w * 16 + srow) * 384 + sch * 8;
  const u16* Xp1 = Xp0 + 128 * 384;

  f32x4 acc[4][4];
  const f32x4 zero = {0.f, 0.f, 0.f, 0.f};
  #pragma unroll
  for (int ji = 0; ji < 4; ++ji)
    #pragma unroll
    for (int ci = 0; ci < 4; ++ci) acc[ji][ci] = zero;

  GEMM_PIPELINE();

  __syncthreads();                                 // full drain; loop done, LDS reusable
  float* scr = (float*)lds;                        // 128 x 68-padded f32 tile (34.8KB)
  const int n0im = jt * 64;

  #pragma unroll
  for (int t = 0; t < 4; ++t) {
    #pragma unroll
    for (int ci = 0; ci < 4; ++ci) {
      const int c_loc = wcg * 64 + ci * 16 + l15;
      float4 pr = PRM[c_loc];
      #pragma unroll
      for (int ji = 0; ji < 4; ++ji) {
        const int n_loc = wjg * 16 + ji * 4 + g;
        float zz = __fadd_rn(acc[ji][ci][t], pr.w);                        // + bias
        zz = __fadd_rn(__fmul_rn(__fsub_rn(zz, pr.y), pr.x), pr.z);        // BN, ref order
        scr[c_loc * 68 + n_loc] = zz;
      }
    }
    __syncthreads();
    #pragma unroll
    for (int it = 0; it < 4; ++it) {
      int slot = tid + it * 512;                   // 2048 slots = 128 rows x 16 float4
      int c = slot >> 4, li = slot & 15;
      float4 val = *(const float4*)&scr[c * 68 + li * 4];
      *(float4*)&out[(((size_t)(t * 16 + b) * 384) + m0 + c) * 1024 + n0im + li * 4] = val;
    }
    __syncthreads();
  }
}

extern "C" void kernel_launch(void* const* d_in, const int* in_sizes, int n_in,
                              void* d_out, int out_size, void* d_ws, size_t ws_size,
                              hipStream_t stream) {
  (void)in_sizes; (void)n_in; (void)out_size; (void)ws_size;
  const float* x   = (const float*)d_in[0];
  const float* qw  = (const float*)d_in[1];
  const float* qg  = (const float*)d_in[2];
  const float* qbt = (const float*)d_in[3];
  const float* qm  = (const float*)d_in[4];
  const float* qv  = (const float*)d_in[5];
  const float* kw  = (const float*)d_in[6];
  const float* kg  = (const float*)d_in[7];
  const float* kbt = (const float*)d_in[8];
  const float* km  = (const float*)d_in[9];
  const float* kv  = (const float*)d_in[10];
  const float* vw  = (const float*)d_in[11];
  const float* vg  = (const float*)d_in[12];
  const float* vbt = (const float*)d_in[13];
  const float* vm  = (const float*)d_in[14];
  const float* vv  = (const float*)d_in[15];
  const float* pw  = (const float*)d_in[16];
  const float* pg  = (const float*)d_in[17];
  const float* pbt = (const float*)d_in[18];
  const float* pm  = (const float*)d_in[19];
  const float* pv  = (const float*)d_in[20];
  const float* pbias = (const float*)d_in[21];

  char* ws = (char*)d_ws;
  u16* xs    = (u16*)ws;                    // (B,N,T,C) bf16 spikes (50 MB); reused as xp
  u8*  sp    = (u8*)(ws + 50331648);        // q,k,v spike nibbles, u8 per (n,c): 3 x 6 MB
  u16* Wstk  = (u16*)(ws + 69206016);       // [1152][384] bf16
  u16* Pw    = (u16*)(ws + 70090752);       // [384][384] bf16
  float4* BNP = (float4*)(ws + 70385664);   // [1152]
  float4* PP  = (float4*)(ws + 70404096);   // [384]

  k_convert<<<2310, 256, 0, stream>>>(qw, kw, vw, pw, qg, qbt, qm, qv, kg, kbt, km, kv,
                                      vg, vbt, vm, vv, pg, pbt, pm, pv, pbias,
                                      Wstk, Pw, BNP, PP);
  k_lif_in<<<dim3(16, 6, 16), 256, 0, stream>>>(x, xs);
  k_qkv<<<dim3(16, 9, 16), 512, 0, stream>>>(Wstk, xs, BNP, sp);
  k_attn<<<4096, 256, 0, stream>>>(sp, xs);          // xp aliases xs (xs dead after k_qkv)
  k_proj<<<dim3(16, 3, 16), 512, 0, stream>>>(Pw, xs, PP, (float*)d_out);
}

// Round 6
// 130.274 us; speedup vs baseline: 1.5862x; 1.0928x over previous
//
#include <hip/hip_runtime.h>

typedef unsigned short u16;
typedef unsigned char u8;
typedef unsigned int u32;
typedef float f32x4 __attribute__((ext_vector_type(4)));
typedef __bf16 bf16x8 __attribute__((ext_vector_type(8)));

#define SPB 6291456      // bytes per packed branch: B*N*C = 16*1024*384 (u8, 4 t-bits)

// ---- async global->LDS, 16B per lane, dest = wave-uniform base + lane*16 ----
__device__ __forceinline__ void gll16(const void* g, void* l) {
  __builtin_amdgcn_global_load_lds((const __attribute__((address_space(1))) void*)g,
                                   (__attribute__((address_space(3))) void*)l, 16, 0, 0);
}

// expand 8 packed spike-bytes (bit t) -> 8 bf16 {0,1} as uint4
__device__ __forceinline__ uint4 expand8(uint2 v, u32 t) {
  u32 a = v.x >> t, b = v.y >> t;
  uint4 r;
  r.x = ((a & 1u) ? 0x3F80u : 0u) | ((a & 0x100u) ? 0x3F800000u : 0u);
  r.y = ((a & 0x10000u) ? 0x3F80u : 0u) | ((a & 0x1000000u) ? 0x3F800000u : 0u);
  r.z = ((b & 1u) ? 0x3F80u : 0u) | ((b & 0x100u) ? 0x3F800000u : 0u);
  r.w = ((b & 0x10000u) ? 0x3F80u : 0u) | ((b & 0x1000000u) ? 0x3F800000u : 0u);
  return r;
}

// ---------------- K0: weights -> bf16 (stacked q,k,v), BN params fused ----------------
__global__ __launch_bounds__(256) void k_convert(
    const float* __restrict__ qw, const float* __restrict__ kw,
    const float* __restrict__ vw, const float* __restrict__ pw,
    const float* __restrict__ qg, const float* __restrict__ qbt,
    const float* __restrict__ qm, const float* __restrict__ qv,
    const float* __restrict__ kg, const float* __restrict__ kbt,
    const float* __restrict__ km, const float* __restrict__ kv,
    const float* __restrict__ vg, const float* __restrict__ vbt,
    const float* __restrict__ vm, const float* __restrict__ vv,
    const float* __restrict__ pg, const float* __restrict__ pbt,
    const float* __restrict__ pm, const float* __restrict__ pv,
    const float* __restrict__ pbias,
    u16* __restrict__ Wstk, u16* __restrict__ Pw,
    float4* __restrict__ BNP, float4* __restrict__ PP) {
  int tid = blockIdx.x * 256 + threadIdx.x;
  if (tid < 442368) {               // Wstk[1152][384]
    int r = tid / 384, c = tid - r * 384;
    const float* src = (r < 384) ? qw : (r < 768) ? kw : vw;
    int rr = (r >= 768) ? r - 768 : (r >= 384) ? r - 384 : r;
    unsigned int u = __float_as_uint(src[rr * 384 + c]);
    u = (u + 0x7FFFu + ((u >> 16) & 1u)) >> 16;   // RNE to bf16
    Wstk[tid] = (u16)u;
  } else if (tid < 589824) {        // Pw[384][384]
    int i = tid - 442368;
    unsigned int u = __float_as_uint(pw[i]);
    u = (u + 0x7FFFu + ((u >> 16) & 1u)) >> 16;
    Pw[i] = (u16)u;
  } else if (tid < 590976) {        // BNP[1152] = {inv, mean, beta, -}
    int r = tid - 589824;
    int br = r / 384, ch = r - br * 384;
    const float* g  = (br == 0) ? qg  : (br == 1) ? kg  : vg;
    const float* bt = (br == 0) ? qbt : (br == 1) ? kbt : vbt;
    const float* m  = (br == 0) ? qm  : (br == 1) ? km  : vm;
    const float* va = (br == 0) ? qv  : (br == 1) ? kv  : vv;
    float inv = g[ch] / sqrtf(va[ch] + 1e-5f);
    BNP[r] = make_float4(inv, m[ch], bt[ch], 0.f);
  } else if (tid < 591360) {        // PP[384] = {inv, mean, beta, bias}
    int ch = tid - 590976;
    float inv = pg[ch] / sqrtf(pv[ch] + 1e-5f);
    PP[ch] = make_float4(inv, pm[ch], pbt[ch], pbias[ch]);
  }
}

// ---------------- K1: input LIF -> packed nibble xsb[(b*1024+n)*384 + c] --------------
__global__ __launch_bounds__(256) void k_lif_in(const float* __restrict__ x, u8* __restrict__ xsb) {
  const int nt = blockIdx.x, ct = blockIdx.y, b = blockIdx.z;
  const int tid = threadIdx.x;
  const int nj = tid & 63, cr = tid >> 6;
  const int c0 = ct * 64, n0 = nt * 64;
  __shared__ u32 nibs[64 * 65];     // [nj][c], +1-pad (u32) -> conflict-free
  float v[16];
  u32 nib[16];
  #pragma unroll
  for (int i = 0; i < 16; ++i) { v[i] = 0.f; nib[i] = 0u; }
  for (int t = 0; t < 4; ++t) {
    const float* xr = x + (((t * 16 + b) * 384 + c0 + cr) * 1024) + n0 + nj;
    #pragma unroll
    for (int it = 0; it < 16; ++it) {
      float xv = xr[it * 4096];
      float vv = v[it];
      float h = __fadd_rn(vv, __fmul_rn(__fsub_rn(xv, vv), 0.5f));  // v + (x-v)/2, exact order
      bool s = h >= 1.f;
      v[it] = s ? 0.f : h;
      nib[it] |= (s ? 1u : 0u) << t;
    }
  }
  #pragma unroll
  for (int it = 0; it < 16; ++it) nibs[nj * 65 + cr + it * 4] = nib[it];
  __syncthreads();
  const int n = tid >> 2, ch = tid & 3;
  u32 w0[4];
  #pragma unroll
  for (int q = 0; q < 4; ++q) {
    u32 acc = 0;
    #pragma unroll
    for (int i = 0; i < 4; ++i)
      acc |= (nibs[n * 65 + ch * 16 + q * 4 + i] & 0xFu) << (8 * i);
    w0[q] = acc;
  }
  *(uint4*)(xsb + ((size_t)(b * 1024 + n0 + n)) * 384 + c0 + ch * 16) =
      make_uint4(w0[0], w0[1], w0[2], w0[3]);
}

// ======================================================================================
// Pipelined GEMM core v3: BM=128 (c rows), BN=256 (j = 64 n x 4 t), BK=32, 512 thr.
// W: bf16 via global_load_lds. X: packed bits -> reg load (uint2) -> expand -> ds_write,
// same chunk-swizzled LDS layout as v2 (verified 0 bank conflicts).
// 3 buffers (72KB -> 2 blocks/CU), 2 stages in flight, counted vmcnt, raw barriers.
// ======================================================================================
#define GISSUE(kt) do { \
    gll16(Wp + (kt) * 32, &lds[((kt) % 3) * 12288 + wst]); \
    xr0[(kt) % 3] = *(const uint2*)(Xb0 + (kt) * 32); \
    xr1[(kt) % 3] = *(const uint2*)(Xb1 + (kt) * 32); \
  } while (0)

#define GWRITE(kt) do { \
    *(uint4*)&lds[((kt) % 3) * 12288 + 4096 + wst + lx8] = expand8(xr0[(kt) % 3], t_row); \
    *(uint4*)&lds[((kt) % 3) * 12288 + 8192 + wst + lx8] = expand8(xr1[(kt) % 3], t_row); \
  } while (0)

#define COMPUTE(bufi) do { \
    const u16* lb_ = &lds[(bufi) * 12288]; \
    bf16x8 ax[4], bw[4]; \
    _Pragma("unroll") \
    for (int ji = 0; ji < 4; ++ji) \
      ax[ji] = *(const bf16x8*)&lb_[4096 + (wjg * 64 + ji * 16 + l15) * 32 + swoff]; \
    _Pragma("unroll") \
    for (int ci = 0; ci < 4; ++ci) \
      bw[ci] = *(const bf16x8*)&lb_[(wcg * 64 + ci * 16 + l15) * 32 + swoff]; \
    __builtin_amdgcn_s_setprio(1); \
    _Pragma("unroll") \
    for (int ji = 0; ji < 4; ++ji) \
      _Pragma("unroll") \
      for (int ci = 0; ci < 4; ++ci) \
        acc[ji][ci] = __builtin_amdgcn_mfma_f32_16x16x32_bf16(ax[ji], bw[ci], acc[ji][ci], 0, 0, 0); \
    __builtin_amdgcn_s_setprio(0); \
  } while (0)

#define GSTEP(kt, VN, ISS) do { \
    asm volatile("s_waitcnt vmcnt(" #VN ")" ::: "memory"); \
    GWRITE(kt); \
    asm volatile("s_waitcnt lgkmcnt(0)" ::: "memory"); \
    __builtin_amdgcn_s_barrier(); \
    asm volatile("" ::: "memory"); \
    ISS; \
    COMPUTE((kt) % 3); \
  } while (0)

#define GEMM_PIPELINE() do { \
    GISSUE(0); GISSUE(1); \
    GSTEP(0, 3, GISSUE(2)); \
    GSTEP(1, 3, GISSUE(3)); \
    GSTEP(2, 3, GISSUE(4)); \
    GSTEP(3, 3, GISSUE(5)); \
    GSTEP(4, 3, GISSUE(6)); \
    GSTEP(5, 3, GISSUE(7)); \
    GSTEP(6, 3, GISSUE(8)); \
    GSTEP(7, 3, GISSUE(9)); \
    GSTEP(8, 3, GISSUE(10)); \
    GSTEP(9, 3, GISSUE(11)); \
    GSTEP(10, 3, ); \
    GSTEP(11, 0, ); \
  } while (0)

#define GEMM_SETUP(WSRC, XSRC) \
  const int tid = threadIdx.x; \
  const int w = tid >> 6, l = tid & 63; \
  const int wjg = w >> 1, wcg = w & 1; \
  const int l15 = tid & 15; \
  const int swoff = (((tid & 63) >> 4) ^ ((l15 >> 1) & 3)) * 8; \
  const int m0 = mt * 128; \
  const int wst = w * 512; \
  const int lx8 = l * 8; \
  const int row = w * 16 + (l >> 2); \
  const u32 t_row = (u32)(row & 3); \
  const int sch = (l & 3) ^ ((l >> 3) & 3); \
  const u16* Wp = (WSRC) + (m0 + row) * 384 + sch * 8; \
  const u8* Xb0 = (XSRC) + ((size_t)(b * 1024 + jt * 64 + (row >> 2))) * 384 + sch * 8; \
  const u8* Xb1 = Xb0 + 32 * 384; \
  uint2 xr0[3], xr1[3]; \
  f32x4 acc[4][4]; \
  const f32x4 zero = {0.f, 0.f, 0.f, 0.f}; \
  _Pragma("unroll") \
  for (int ji = 0; ji < 4; ++ji) \
    _Pragma("unroll") \
    for (int ci = 0; ci < 4; ++ci) acc[ji][ci] = zero;

// ---------------- K2: stacked qkv GEMM + BN + LIF -> sp u8 (4 t-bits per (n,c)) -------
__global__ __launch_bounds__(512, 4) void k_qkv(
    const u16* __restrict__ Wstk, const u8* __restrict__ xsb,
    const float4* __restrict__ BNP, u8* __restrict__ sp) {
  const int jt = blockIdx.x, mt = blockIdx.y, b = blockIdx.z;
  __shared__ u16 lds[36864];                      // 3 x 24KB buffers
  __shared__ float4 PRM[128];
  if (threadIdx.x < 128) PRM[threadIdx.x] = BNP[mt * 128 + threadIdx.x];
  __syncthreads();

  GEMM_SETUP(Wstk, xsb);
  GEMM_PIPELINE();

  // epilogue: BN + 4-step LIF per lane (acc regs = t), pack 4 spike bits -> one u8
  const int br = mt / 3;
  const int cb = (mt - br * 3) * 128;
  const int g = (tid & 63) >> 4;
  u8* spW = sp + (size_t)br * SPB;
  #pragma unroll
  for (int ci = 0; ci < 4; ++ci) {
    const int c_loc = wcg * 64 + ci * 16 + l15;
    float4 pr = PRM[c_loc];
    #pragma unroll
    for (int ji = 0; ji < 4; ++ji) {
      f32x4 a = acc[ji][ci];
      u32 bits = 0;
      float v = 0.f;
      #pragma unroll
      for (int t = 0; t < 4; ++t) {
        float z = __fadd_rn(__fmul_rn(__fsub_rn(a[t], pr.y), pr.x), pr.z);  // BN, ref order
        float h = __fadd_rn(v, __fmul_rn(__fsub_rn(z, v), 0.5f));            // LIF step
        bool s = h >= 1.f;
        v = s ? 0.f : h;
        bits |= (s ? 1u : 0u) << t;
      }
      const int n_comb = b * 1024 + jt * 64 + wjg * 16 + ji * 4 + g;
      spW[(size_t)n_comb * 384 + cb + c_loc] = (u8)bits;
    }
  }
}

// ---------------- K3: attn = sum_ch(k&v) per head, LIF(0.5) -> xpb = q & mask ---------
__global__ __launch_bounds__(256) void k_attn(const u8* __restrict__ sp, u8* __restrict__ xpb) {
  const int gw = blockIdx.x * 4 + (threadIdx.x >> 6);
  const int l = threadIdx.x & 63;
  const int b = gw >> 10, n = gw & 1023;
  const u8* qB = sp;
  const u8* kB = sp + SPB;
  const u8* vB = sp + 2 * SPB;
  const int base = (b * 1024 + n) * 384 + l * 6;   // byte index; lane covers 6 channels
  u16 qu[3], ku[3], vu[3];
  #pragma unroll
  for (int i = 0; i < 3; ++i) {
    qu[i] = *(const u16*)(qB + base + 2 * i);
    ku[i] = *(const u16*)(kB + base + 2 * i);
    vu[i] = *(const u16*)(vB + base + 2 * i);
  }
  u32 s = 0;                        // 4 per-t byte sums packed in a u32
  #pragma unroll
  for (int i = 0; i < 3; ++i) {
    u32 a = (u32)(ku[i] & vu[i]);
    #pragma unroll
    for (int t = 0; t < 4; ++t) {
      u32 x = (a >> t) & 0x0101u;
      s += ((x + (x >> 8)) & 3u) << (8 * t);
    }
  }
  s += __shfl_xor(s, 1);
  s += __shfl_xor(s, 2);
  s += __shfl_xor(s, 4);            // 8 lanes == one 48-channel head; bytes <= 48
  float v = 0.f;
  u32 m8 = 0;
  #pragma unroll
  for (int t = 0; t < 4; ++t) {
    float attn = (float)((s >> (8 * t)) & 0xFFu);
    float h = __fadd_rn(v, __fmul_rn(__fsub_rn(attn, v), 0.5f));
    bool sk = h >= 0.5f;
    v = sk ? 0.f : h;
    m8 |= (sk ? 1u : 0u) << t;
  }
  const u16 mm = (u16)(m8 * 0x0101u);
  u16* dst = (u16*)(xpb + base);
  #pragma unroll
  for (int i = 0; i < 3; ++i) dst[i] = qu[i] & mm;
}

// ---------------- K4: P GEMM + bias + BN -> out fp32 (LDS-transposed coalesced store) -
__global__ __launch_bounds__(512, 4) void k_proj(
    const u16* __restrict__ Pw, const u8* __restrict__ xpb,
    const float4* __restrict__ PP, float* __restrict__ out) {
  const int jt = blockIdx.x, mt = blockIdx.y, b = blockIdx.z;
  __shared__ u16 lds[36864];
  __shared__ float4 PRM[128];
  if (threadIdx.x < 128) PRM[threadIdx.x] = PP[mt * 128 + threadIdx.x];
  __syncthreads();

  GEMM_SETUP(Pw, xpb);
  GEMM_PIPELINE();

  __syncthreads();                                 // full drain; loop done, LDS reusable
  float* scr = (float*)lds;                        // 128 x 68-padded f32 tile (34.8KB)
  const int n0im = jt * 64;
  const int g = (tid & 63) >> 4;

  #pragma unroll
  for (int t = 0; t < 4; ++t) {
    #pragma unroll
    for (int ci = 0; ci < 4; ++ci) {
      const int c_loc = wcg * 64 + ci * 16 + l15;
      float4 pr = PRM[c_loc];
      #pragma unroll
      for (int ji = 0; ji < 4; ++ji) {
        const int n_loc = wjg * 16 + ji * 4 + g;
        float zz = __fadd_rn(acc[ji][ci][t], pr.w);                        // + bias
        zz = __fadd_rn(__fmul_rn(__fsub_rn(zz, pr.y), pr.x), pr.z);        // BN, ref order
        scr[c_loc * 68 + n_loc] = zz;
      }
    }
    __syncthreads();
    #pragma unroll
    for (int it = 0; it < 4; ++it) {
      int slot = tid + it * 512;                   // 2048 slots = 128 rows x 16 float4
      int c = slot >> 4, li = slot & 15;
      float4 val = *(const float4*)&scr[c * 68 + li * 4];
      *(float4*)&out[(((size_t)(t * 16 + b) * 384) + mt * 128 + c) * 1024 + n0im + li * 4] = val;
    }
    __syncthreads();
  }
}

extern "C" void kernel_launch(void* const* d_in, const int* in_sizes, int n_in,
                              void* d_out, int out_size, void* d_ws, size_t ws_size,
                              hipStream_t stream) {
  (void)in_sizes; (void)n_in; (void)out_size; (void)ws_size;
  const float* x   = (const float*)d_in[0];
  const float* qw  = (const float*)d_in[1];
  const float* qg  = (const float*)d_in[2];
  const float* qbt = (const float*)d_in[3];
  const float* qm  = (const float*)d_in[4];
  const float* qv  = (const float*)d_in[5];
  const float* kw  = (const float*)d_in[6];
  const float* kg  = (const float*)d_in[7];
  const float* kbt = (const float*)d_in[8];
  const float* km  = (const float*)d_in[9];
  const float* kv  = (const float*)d_in[10];
  const float* vw  = (const float*)d_in[11];
  const float* vg  = (const float*)d_in[12];
  const float* vbt = (const float*)d_in[13];
  const float* vm  = (const float*)d_in[14];
  const float* vv  = (const float*)d_in[15];
  const float* pw  = (const float*)d_in[16];
  const float* pg  = (const float*)d_in[17];
  const float* pbt = (const float*)d_in[18];
  const float* pm  = (const float*)d_in[19];
  const float* pv  = (const float*)d_in[20];
  const float* pbias = (const float*)d_in[21];

  char* ws = (char*)d_ws;
  u8*  xsb   = (u8*)ws;                     // input spikes, packed nibbles (6.3 MB)
  u8*  sp    = (u8*)(ws + 6291456);         // q,k,v spike nibbles (3 x 6.3 MB)
  u8*  xpb   = (u8*)(ws + 25165824);        // q&attn spikes, packed nibbles (6.3 MB)
  u16* Wstk  = (u16*)(ws + 31457280);       // [1152][384] bf16
  u16* Pw    = (u16*)(ws + 32342016);       // [384][384] bf16
  float4* BNP = (float4*)(ws + 32636928);   // [1152]
  float4* PP  = (float4*)(ws + 32655360);   // [384]

  k_convert<<<2310, 256, 0, stream>>>(qw, kw, vw, pw, qg, qbt, qm, qv, kg, kbt, km, kv,
                                      vg, vbt, vm, vv, pg, pbt, pm, pv, pbias,
                                      Wstk, Pw, BNP, PP);
  k_lif_in<<<dim3(16, 6, 16), 256, 0, stream>>>(x, xsb);
  k_qkv<<<dim3(16, 9, 16), 512, 0, stream>>>(Wstk, xsb, BNP, sp);
  k_attn<<<4096, 256, 0, stream>>>(sp, xpb);
  k_proj<<<dim3(16, 3, 16), 512, 0, stream>>>(Pw, xpb, PP, (float*)d_out);
}